// Round 1
// baseline (60.603 us; speedup 1.0000x reference)
//
#include <hip/hip_runtime.h>
#include <math.h>

#define N_WIRES 18
#define BATCH 64

// Closed-form evaluation of the quantum circuit (derivation verified: absmax 0.0
// in earlier rounds):
//   theta[b,i] = (a[b,i]-min)/(max-min)*2pi - pi      (min/max over whole batch)
//   <Z_i>      = cos(alpha_i)cos(beta_i)cos(theta_i)
//                - sin(beta_i)sin(theta_i)*cos(theta_{i-1})*cos(theta_{i+1})
//   out[b]     = head_b + sum_i head_w[i]*<Z_i>
//
// Round-4 structure: same one-wave / one-row-per-lane plan, but MINIMIZED CODE
// FOOTPRINT. A lone workgroup cold-fetches its instructions serially (round 1:
// libm trig cost ~58 us purely in I-fetch), so straight-line unrolled code is
// the remaining kernel-side cost. All 18-iteration loops are rolled
// (#pragma unroll 1); the accumulation streams a 3-wide rolling window
// (c_prev, c_cur / s_cur, c_next) so nothing is runtime-indexed in registers
// (runtime-indexed register arrays spill to scratch). Row values are re-read
// from L1 on the second pass instead of being pinned in 18 VGPRs.
__global__ __launch_bounds__(64) void qc_closed_form(
        const float* __restrict__ a,       // (BATCH, N_WIRES)
        const float* __restrict__ params,  // (N_WIRES, 3)
        const float* __restrict__ head_w,  // (1, N_WIRES)
        const float* __restrict__ head_b,  // (1,)
        float* __restrict__ out)           // (BATCH,)
{
    const int t = threadIdx.x;  // 0..63 == batch row
    __shared__ float s_cA[N_WIRES];
    __shared__ float s_cB[N_WIRES];

    // per-wire coefficients (lanes 0..17), folded with head weights
    if (t < N_WIRES) {
        float al = params[3 * t];
        float be = params[3 * t + 1];
        float w  = head_w[t];
        s_cA[t] = __cosf(al) * __cosf(be) * w;
        s_cB[t] = __sinf(be) * w;
    }

    const float* row = a + t * N_WIRES;

    // Pass 1: per-row min/max (rolled loop; loads fill L1 for pass 2)
    float mn = row[0];
    float mx = mn;
    #pragma unroll 1
    for (int i = 1; i < N_WIRES; ++i) {
        float x = row[i];
        mn = fminf(mn, x);
        mx = fmaxf(mx, x);
    }
    // wave-64 butterfly -> global min/max (6 steps, keep unrolled: constant offsets)
    #pragma unroll
    for (int off = 32; off > 0; off >>= 1) {
        mn = fminf(mn, __shfl_xor(mn, off));
        mx = fmaxf(mx, __shfl_xor(mx, off));
    }
    const float scale = 6.28318530717958647692f / (mx - mn);
    const float pi    = 3.14159265358979323846f;

    __syncthreads();  // single wave: cheap; makes s_cA/s_cB visible

    // Pass 2: streaming closed-form accumulation with a 3-register window.
    // At step i: c_prev = ct[i-1] (1.0 at i=0), c_cur/s_cur = ct[i]/st[i],
    // c_next = ct[i+1] (1.0 at i=17, handled in the epilogue).
    float th0 = (row[0] - mn) * scale - pi;
    float c_prev = 1.0f;
    float c_cur  = __cosf(th0);
    float s_cur  = __sinf(th0);

    float acc = head_b[0];
    #pragma unroll 1
    for (int i = 0; i < N_WIRES - 1; ++i) {
        float th = (row[i + 1] - mn) * scale - pi;   // L1 hit (pass 1 warmed it)
        float c_next = __cosf(th);
        float s_next = __sinf(th);
        acc = fmaf(s_cA[i], c_cur, acc);             // LDS broadcast (uniform idx)
        acc -= s_cB[i] * s_cur * c_prev * c_next;
        c_prev = c_cur;
        c_cur  = c_next;
        s_cur  = s_next;
    }
    // i = 17: ct[18] == 1.0
    acc = fmaf(s_cA[N_WIRES - 1], c_cur, acc);
    acc -= s_cB[N_WIRES - 1] * s_cur * c_prev;

    out[t] = acc;
}

extern "C" void kernel_launch(void* const* d_in, const int* in_sizes, int n_in,
                              void* d_out, int out_size, void* d_ws, size_t ws_size,
                              hipStream_t stream) {
    const float* a      = (const float*)d_in[0];  // state_batch (64,18)
    const float* params = (const float*)d_in[1];  // (18,3)
    const float* head_w = (const float*)d_in[2];  // (1,18)
    const float* head_b = (const float*)d_in[3];  // (1,)
    float* out = (float*)d_out;                   // (64,)
    qc_closed_form<<<1, 64, 0, stream>>>(a, params, head_w, head_b, out);
}